// Round 15
// baseline (849.677 us; speedup 1.0000x reference)
//
#include <hip/hip_runtime.h>
#include <stdint.h>

#define THR 10.0f
#define AGT __HIP_MEMORY_SCOPE_AGENT

// ---- workspace layout (bytes) ----
// s1m x8 (u16 per 2x2 block): 8 * 262,144 = 2,097,152 at 0            (t & 7)
// p2m x8 (u64 per cell):      8 *  32,768 =   262,144 at 2,097,152    (t & 7)
// barrier: u32[256] at 2,359,296
static constexpr size_t OFF_P2  = 2097152;
static constexpr size_t OFF_BAR = 2359296;

static __device__ __forceinline__ uint64_t ldu64(const uint64_t* p) {
    return __hip_atomic_load(p, __ATOMIC_RELAXED, AGT);
}
static __device__ __forceinline__ void stu64(uint64_t* p, uint64_t v) {
    __hip_atomic_store(p, v, __ATOMIC_RELAXED, AGT);
}

__global__ __launch_bounds__(256) void zero_bar(uint32_t* __restrict__ bar) {
    if (threadIdx.x < 256) bar[threadIdx.x] = 0u;
}

// Group-local barrier (64 blocks of one batch group); all dataflow is
// intra-group. bar[g*32]: arrival counter (RMW); bar[g*32+16]: go epoch
// (polled with relaxed agent LOAD).
__device__ __forceinline__ void gbar(uint32_t* bar, int bid, uint32_t n) {
    __syncthreads();                       // drains vmcnt: sc1 stores done
    if (threadIdx.x == 0) {
        uint32_t* base = bar + (bid >> 6) * 32;
        uint32_t a = __hip_atomic_fetch_add(base, 1u, __ATOMIC_RELAXED, AGT);
        if (a == 64u * n - 1u)
            __hip_atomic_fetch_add(base + 16, 1u, __ATOMIC_RELAXED, AGT);
        while (__hip_atomic_load(base + 16, __ATOMIC_RELAXED, AGT) < n)
            __builtin_amdgcn_s_sleep(2);
    }
    __syncthreads();
}

// Persistent kernel, 512 blocks x 512 threads, 2 blocks/CU = 16 waves/CU.
// Fused-role block: waves 0-3 = verbatim R12 A-path (conv1+LIF1+WTA strip)
// + L3; waves 4-7 = verbatim R12 B-path (pool1+conv2+LIF2+WTA+pool2 tile).
// Roles share stage syncs, so A compute overlaps B's sc1/LDS stalls on the
// same CU (placement-proof, unlike R13's per-block roles).
// Superstep k (k=0..6): A(4k..4k+3) ; L3(4k-8..4k-5) ; B(4k-4..4k-1).
__global__ __launch_bounds__(512, 4) void spike_persist(
    const float* __restrict__ x,    // (20,8,1,256,256)
    const float* __restrict__ w1,   // (4,1,5,5)
    const float* __restrict__ w2,   // (36,4,5,5)
    const float* __restrict__ w3,   // (1,36,7,7)
    float* __restrict__ out,        // (20,8,1,21,21)
    uint8_t* __restrict__ s1b,      // 8 buffers of u16[8][128][128]
    uint8_t* __restrict__ p2b,      // 8 buffers of u64[8][441]
    uint32_t* __restrict__ bar)
{
    __shared__ float    xs[2112];    // A: 8 x 264 input rows (halo 2)
    __shared__ uint64_t st64[279];   // B: staged s1m 31 rows x 9 u64
    __shared__ float    ps[400];     // B: 4 ch x 10 x 10 pooled tile (halo 2)
    __shared__ float    mem_s[1296]; // B: 36 ch x 36 planes (pitch 6)
    __shared__ float    bm_s[324];   // B: 36 ch x 9 blocks (pitch 3)
    __shared__ int      wc_s[36];
    __shared__ uint32_t p2a[18];     // B: 9 cells x 2 words of channel bits

    const int tid = threadIdx.x;
    const int bid = blockIdx.x;
    const int bt = bid >> 6;         // batch (both roles)
    const bool isA = tid < 256;
    const int btid = tid & 255;      // role-local tid
    const int wv = (tid >> 6) & 3;   // role-local wave 0..3
    const int lane = tid & 63;
    uint32_t nbar = 0;

    // ================= role-local state =================
    // ---- A role: 64 row-strips (4 rows each) per batch
    float m1r[4][2][2];
    int aoff[9]; uint32_t avalm = 0; int s1soff64 = 0;
    float w3v[36]; float m3r[2] = {0.f, 0.f};
    bool l3in[2], l3v[2]; int l3o[2]; int lid3 = 0;
    // ---- B role: 8x8 tiles (uneven splits) per batch
    float m2r[9];
    int boff[2]; uint32_t bvalm = 0; int d16 = 0;
    int oy2 = 0, ox2 = 0, th2 = 0, tw2 = 0;
    bool act = false; int prA = 0, pcA = 0;
    uint64_t pf0 = 0, pf1 = 0;

    if (isA) {
        const int r0 = (bid & 63) * 4;
        const int tr = tid >> 7, tc = tid & 127;
#pragma unroll
        for (int c = 0; c < 4; c++)
#pragma unroll
            for (int dy = 0; dy < 2; dy++)
#pragma unroll
                for (int dx = 0; dx < 2; dx++) m1r[c][dy][dx] = 0.f;
#pragma unroll
        for (int i = 0; i < 9; i++) {
            int idx = tid + i * 256;
            int row = idx / 264, col = idx - row * 264;
            int gy = r0 + row - 2, gx = col - 2;
            if ((idx < 2112) && gy >= 0 && gy < 256 && gx >= 0 && gx < 256)
                avalm |= 1u << i;
            aoff[i] = gy * 256 + gx;
        }
        s1soff64 = (bt * 128 + (r0 >> 1) + tr) * 32 + (tc >> 2);
#pragma unroll
        for (int c = 0; c < 36; c++) w3v[c] = (lane < 49) ? w3[c * 49 + lane] : 0.f;
        lid3 = (bid & 63) * 4 + wv;
        const int kyl = lane / 7, kxl = lane % 7;
#pragma unroll
        for (int rep = 0; rep < 2; rep++) {
            int o = lid3 + rep * 256;
            int rr = o / 21, cl = o - rr * 21;
            int yy = rr + kyl - 3, xx = cl + kxl - 3;
            l3in[rep] = o < 441;
            l3v[rep] = (o < 441) && (lane < 49) && yy >= 0 && yy < 21 && xx >= 0 && xx < 21;
            l3o[rep] = bt * 441 + yy * 21 + xx;      // u64 units
        }
    } else {
        const int tIdx = bid & 63;
        const int tyi = tIdx >> 3, txi = tIdx & 7;
        oy2 = tyi < 5 ? 6 * tyi : 30 + 4 * (tyi - 5);
        ox2 = txi < 5 ? 6 * txi : 30 + 4 * (txi - 5);
        th2 = tyi < 5 ? 6 : 4;
        tw2 = txi < 5 ? 6 : 4;
        const int pr = lane / 6, pc = lane - 6 * pr;
        act = (pr < th2) && (pc < tw2);
        prA = pr > 5 ? 0 : pr; pcA = pc;
#pragma unroll
        for (int i = 0; i < 9; i++) m2r[i] = 0.f;
        const int rb0 = 3 * oy2 - 6;
        const int cb0 = (3 * ox2 - 6) >> 1;
        const int cq0 = cb0 >> 1;
        d16 = 2 * (cb0 & 1);
#pragma unroll
        for (int i = 0; i < 2; i++) {
            int idx = btid + i * 256;
            int row = idx / 9, q = idx - 9 * row;
            int grow = rb0 + row;
            int ucol = 2 * (cq0 + q);
            if ((idx < 279) && grow >= 0 && grow < 128 && ucol >= 0 && ucol < 64)
                bvalm |= 1u << i;
            boff[i] = (bt * 128 + grow) * 32 + cq0 + q;
        }
    }

    for (int k = 0; k < 7; k++) {
        // post-barrier prefetch of tt=0's B staging (slot written last superstep)
        if (!isA) {
            int tb0 = 4 * k - 4;
            if (tb0 >= 0 && tb0 < 20) {
                const uint64_t* s1r64 = reinterpret_cast<const uint64_t*>(
                    s1b + (size_t)(tb0 & 7) * 262144);
                pf0 = (bvalm & 1u) ? ldu64(s1r64 + boff[0]) : 0ull;
                pf1 = (bvalm & 2u) ? ldu64(s1r64 + boff[1]) : 0ull;
            }
        }

        for (int tt = 0; tt < 4; tt++) {
            const int t = 4 * k + tt;
            const int tb = 4 * k - 4 + tt;
            const int tl = 4 * k - 8 + tt;
            const bool tok = t < 20;
            const bool tbok = (tb >= 0) && (tb < 20);
            const bool tlok = (tl >= 0) && (tl < 20);

            // ---------- S1: A stage xs ; B write staged s1 to LDS ----------
            if (isA && tok) {
                const float* xb = x + ((size_t)t * 8 + bt) * 65536;
#pragma unroll
                for (int i = 0; i < 9; i++) {
                    int idx = tid + i * 256;
                    if (idx < 2112) xs[idx] = ((avalm >> i) & 1u) ? xb[aoff[i]] : 0.f;
                }
            } else if (!isA && tbok) {
                st64[btid] = pf0;
                if (btid + 256 < 279) st64[btid + 256] = pf1;
            }
            __syncthreads();

            // ---------- S2: A conv1+LIF1+WTA+store ; B pool ----------
            if (isA && tok) {
                uint64_t* s1w = reinterpret_cast<uint64_t*>(s1b + (size_t)(t & 7) * 262144);
                const int tr = tid >> 7, tc = tid & 127;
                const float2* xs2 = reinterpret_cast<const float2*>(xs);
                float p[6][6];
#pragma unroll
                for (int i = 0; i < 6; i++)
#pragma unroll
                    for (int j = 0; j < 3; j++) {
                        float2 v = xs2[(2 * tr + i) * 132 + tc + j];
                        p[i][2 * j] = v.x; p[i][2 * j + 1] = v.y;
                    }

                float acc[4][2][2];
#pragma unroll
                for (int c = 0; c < 4; c++)
#pragma unroll
                    for (int dy = 0; dy < 2; dy++)
#pragma unroll
                        for (int dx = 0; dx < 2; dx++) acc[c][dy][dx] = 0.f;
#pragma unroll
                for (int c = 0; c < 4; c++)
#pragma unroll
                    for (int ky = 0; ky < 5; ky++)
#pragma unroll
                        for (int kx = 0; kx < 5; kx++) {
                            float w = w1[c * 25 + ky * 5 + kx];
#pragma unroll
                            for (int dy = 0; dy < 2; dy++)
#pragma unroll
                                for (int dx = 0; dx < 2; dx++)
                                    acc[c][dy][dx] = fmaf(p[dy + ky][dx + kx], w, acc[c][dy][dx]);
                        }

                float mem[4][2][2];
#pragma unroll
                for (int c = 0; c < 4; c++)
#pragma unroll
                    for (int dy = 0; dy < 2; dy++)
#pragma unroll
                        for (int dx = 0; dx < 2; dx++)
                            mem[c][dy][dx] = m1r[c][dy][dx] + acc[c][dy][dx];

                int wc[2][2];
#pragma unroll
                for (int dy = 0; dy < 2; dy++)
#pragma unroll
                    for (int dx = 0; dx < 2; dx++) {
                        int w = 0; float mx = mem[0][dy][dx];
#pragma unroll
                        for (int c = 1; c < 4; c++) {
                            float v = mem[c][dy][dx];
                            if (v > mx) { mx = v; w = c; }
                        }
                        wc[dy][dx] = w;
                    }

                float bm[4];
#pragma unroll
                for (int c = 0; c < 4; c++)
                    bm[c] = fmaxf(fmaxf(mem[c][0][0], mem[c][0][1]),
                                  fmaxf(mem[c][1][0], mem[c][1][1]));

                uint32_t bits = 0;
#pragma unroll
                for (int c = 0; c < 4; c++)
#pragma unroll
                    for (int dy = 0; dy < 2; dy++)
#pragma unroll
                        for (int dx = 0; dx < 2; dx++) {
                            float m = mem[c][dy][dx];
                            bool s = (m >= THR) && (wc[dy][dx] == c) && (m >= bm[c]);
                            m1r[c][dy][dx] = fmaxf((s ? 0.f : m) - 9.0f, 0.f);
                            bits |= (s ? 1u : 0u) << (c * 4 + dy * 2 + dx);
                        }
                uint32_t b32 = bits | ((uint32_t)__shfl_xor((int)bits, 1, 64) << 16);
                uint64_t b64 = (uint64_t)b32 |
                               ((uint64_t)(uint32_t)__shfl_xor((int)b32, 2, 64) << 32);
                if (!(tid & 3)) stu64(s1w + s1soff64, b64);
            } else if (!isA && tbok) {
                if (btid < 100) {
                    int r = btid / 10, cc2 = btid - 10 * (btid / 10);
                    int gy = oy2 - 2 + r, gx = ox2 - 2 + cc2;
                    uint32_t accb = 0;
                    if (r < th2 + 4 && cc2 < tw2 + 4 && gy >= 0 && gy < 42 && gx >= 0 && gx < 42) {
                        const uint16_t* st16 = reinterpret_cast<const uint16_t*>(st64);
#pragma unroll
                        for (int kr = 0; kr < 4; kr++)
#pragma unroll
                            for (int kc = 0; kc < 4; kc++) {
                                uint32_t m = (kr < 3) ? (kc < 3 ? 0xFu : 0x5u)
                                                      : (kc < 3 ? 0x3u : 0x1u);
                                uint32_t v = st16[(3 * r + kr) * 36 + 3 * cc2 + kc + d16];
                                accb |= v & (m * 0x1111u);
                            }
                    }
#pragma unroll
                    for (int ic = 0; ic < 4; ic++)
                        ps[ic * 100 + btid] = ((accb >> (4 * ic)) & 0xFu) ? 1.f : 0.f;
                }
            }
            __syncthreads();

            // ---------- S3: A does L3(tl) ; B conv2 + next prefetch ----------
            if (isA && tlok) {
                const uint64_t* pb64 = reinterpret_cast<const uint64_t*>(
                    p2b + (size_t)(tl & 7) * 32768);
#pragma unroll
                for (int rep = 0; rep < 2; rep++) {
                    if (l3in[rep]) {
                        int o = lid3 + rep * 256;
                        uint64_t v = l3v[rep] ? ldu64(pb64 + l3o[rep]) : 0ull;
                        uint32_t lo = (uint32_t)v, hi = (uint32_t)(v >> 32);
                        float accv = 0.f;
#pragma unroll
                        for (int c = 0; c < 32; c++) accv += ((lo >> c) & 1u) ? w3v[c] : 0.f;
#pragma unroll
                        for (int c = 0; c < 4; c++)  accv += ((hi >> c) & 1u) ? w3v[32 + c] : 0.f;
#pragma unroll
                        for (int off = 32; off; off >>= 1) accv += __shfl_xor(accv, off, 64);
                        float memv3 = m3r[rep] + accv;
                        bool s = memv3 >= THR;
                        if (lane == 0) out[(size_t)tl * 3528 + bt * 441 + o] = s ? 1.f : 0.f;
                        m3r[rep] = fmaxf(s ? 0.f : memv3, 0.f);
                    }
                }
            } else if (!isA && tbok) {
                float pv[4][5][5];
#pragma unroll
                for (int ic = 0; ic < 4; ic++)
#pragma unroll
                    for (int i = 0; i < 5; i++)
#pragma unroll
                        for (int j = 0; j < 5; j++)
                            pv[ic][i][j] = ps[ic * 100 + (prA + i) * 10 + (pcA + j)];

                // prefetch next timestep's staging (hides under conv2)
                {
                    int tbn = tb + 1;
                    if (tt < 3 && tbn >= 0 && tbn < 20) {
                        const uint64_t* s1r64 = reinterpret_cast<const uint64_t*>(
                            s1b + (size_t)(tbn & 7) * 262144);
                        pf0 = (bvalm & 1u) ? ldu64(s1r64 + boff[0]) : 0ull;
                        pf1 = (bvalm & 2u) ? ldu64(s1r64 + boff[1]) : 0ull;
                    }
                }

                for (int cc = 0; cc < 9; cc++) {
                    int c = cc * 4 + wv;                         // wave-uniform
                    const float* wr = w2 + (size_t)__builtin_amdgcn_readfirstlane(c) * 100;
                    float accv = 0.f;
#pragma unroll
                    for (int ic = 0; ic < 4; ic++)
#pragma unroll
                        for (int i = 0; i < 5; i++)
#pragma unroll
                            for (int j = 0; j < 5; j++)
                                accv = fmaf(pv[ic][i][j], wr[ic * 25 + i * 5 + j], accv);
                    float m = act ? (m2r[cc] + accv) : -1e30f;
                    if (lane < 36) mem_s[c * 36 + lane] = m;     // plane == lane
                }
            }
            __syncthreads();

            // ---------- S4: B wc_s + bm_s + p2a zero ----------
            if (!isA && tbok) {
                if (btid < 36) {
                    float mx = mem_s[btid]; int w = 0;
#pragma unroll
                    for (int c = 1; c < 36; c++) {
                        float v = mem_s[c * 36 + btid];
                        if (v > mx) { mx = v; w = c; }
                    }
                    wc_s[btid] = w;
                }
#pragma unroll
                for (int i = 0; i < 2; i++) {
                    int idx = btid + i * 256;
                    if (idx < 324) {
                        int c = idx / 9, blk = idx - 9 * c;
                        int br = blk / 3, bc2 = blk - 3 * br;
                        int l0 = 12 * br + 2 * bc2;
                        float a = mem_s[c * 36 + l0],     bb2 = mem_s[c * 36 + l0 + 1];
                        float d = mem_s[c * 36 + l0 + 6], e   = mem_s[c * 36 + l0 + 7];
                        bm_s[idx] = fmaxf(fmaxf(a, bb2), fmaxf(d, e));
                    }
                }
                if (btid < 18) p2a[btid] = 0;
            }
            __syncthreads();

            // ---------- S5: B m2r update + any/atomicOr ----------
            if (!isA && tbok) {
                const int pr = lane / 6, pc = lane - 6 * pr;
                const int blkl = (pr >> 1) * 3 + (pc >> 1);
                for (int cc = 0; cc < 9; cc++) {
                    int c = cc * 4 + wv;
                    if (act) {
                        float m = mem_s[c * 36 + lane];
                        bool s = (m >= THR) && (wc_s[lane] == c) && (m >= bm_s[c * 9 + blkl]);
                        m2r[cc] = fmaxf((s ? 0.f : m) - 1.0f, 0.f);
                    }
                }
#pragma unroll
                for (int i = 0; i < 2; i++) {
                    int idx = btid + i * 256;
                    if (idx < 324) {
                        int c = idx / 9, blk = idx - 9 * c;
                        int br = blk / 3, bc2 = blk - 3 * br;
                        if (2 * br < th2 && 2 * bc2 < tw2) {
                            int l0 = 12 * br + 2 * bc2;
                            float bmv = bm_s[idx];
                            bool any = false;
#pragma unroll
                            for (int kk = 0; kk < 4; kk++) {
                                int l = l0 + (kk >> 1) * 6 + (kk & 1);
                                float m = mem_s[c * 36 + l];
                                any |= (m >= THR) && (wc_s[l] == c) && (m >= bmv);
                            }
                            if (any)
                                atomicOr(&p2a[(blk << 1) + (c >> 5)], 1u << (c & 31));
                        }
                    }
                }
            }
            __syncthreads();

            // ---------- S6: B p2 store ----------
            if (!isA && tbok) {
                if (btid < 9) {
                    int br = btid / 3, bc2 = btid - 3 * br;
                    if (2 * br < th2 && 2 * bc2 < tw2) {
                        uint64_t* p2w64 = reinterpret_cast<uint64_t*>(
                            p2b + (size_t)(tb & 7) * 32768);
                        int cell = bt * 441 + ((oy2 >> 1) + br) * 21 + (ox2 >> 1) + bc2;
                        uint64_t v = (uint64_t)p2a[btid * 2] |
                                     ((uint64_t)p2a[btid * 2 + 1] << 32);
                        stu64(p2w64 + cell, v);
                    }
                }
            }
            // no sync here: next S1 touches xs/st64 only, protected by S1's sync
        }

        if (k < 6) gbar(bar, bid, ++nbar);
    }
}

extern "C" void kernel_launch(void* const* d_in, const int* in_sizes, int n_in,
                              void* d_out, int out_size, void* d_ws, size_t ws_size,
                              hipStream_t stream) {
    const float* x  = (const float*)d_in[0];
    const float* w1 = (const float*)d_in[1];
    const float* w2 = (const float*)d_in[2];
    const float* w3 = (const float*)d_in[3];
    float* out = (float*)d_out;
    uint8_t* s1 = (uint8_t*)d_ws;
    uint8_t* p2 = (uint8_t*)d_ws + OFF_P2;
    uint32_t* bar = (uint32_t*)((char*)d_ws + OFF_BAR);

    zero_bar<<<1, 256, 0, stream>>>(bar);

    void* args[] = {(void*)&x, (void*)&w1, (void*)&w2, (void*)&w3,
                    (void*)&out, (void*)&s1, (void*)&p2, (void*)&bar};
    hipLaunchCooperativeKernel((void*)spike_persist, dim3(512), dim3(512),
                               args, 0, stream);
}

// Round 16
// 554.695 us; speedup vs baseline: 1.5318x; 1.5318x over previous
//
#include <hip/hip_runtime.h>
#include <stdint.h>

#define THR 10.0f
#define AGT __HIP_MEMORY_SCOPE_AGENT

// ---- workspace layout (bytes) ----
// s1m x8 (u16 per 2x2 block): 8 * 262,144 = 2,097,152 at 0            (t & 7)
// p2m x8 (u64 per cell):      8 *  32,768 =   262,144 at 2,097,152    (t & 7)
// barrier: u32[256] at 2,359,296
static constexpr size_t OFF_P2  = 2097152;
static constexpr size_t OFF_BAR = 2359296;

static __device__ __forceinline__ uint64_t ldu64(const uint64_t* p) {
    return __hip_atomic_load(p, __ATOMIC_RELAXED, AGT);
}
static __device__ __forceinline__ void stu64(uint64_t* p, uint64_t v) {
    __hip_atomic_store(p, v, __ATOMIC_RELAXED, AGT);
}

__global__ __launch_bounds__(256) void zero_bar(uint32_t* __restrict__ bar) {
    if (threadIdx.x < 256) bar[threadIdx.x] = 0u;
}

// Group-local barrier (64 blocks of one batch group).
// bar[g*32]: arrival counter (RMW); bar[g*32+16]: go epoch (load-polled).
__device__ __forceinline__ void gbar(uint32_t* bar, int bid, uint32_t n) {
    __syncthreads();                       // drains vmcnt: sc1 stores done
    if (threadIdx.x == 0) {
        uint32_t* base = bar + (bid >> 6) * 32;
        uint32_t a = __hip_atomic_fetch_add(base, 1u, __ATOMIC_RELAXED, AGT);
        if (a == 64u * n - 1u)
            __hip_atomic_fetch_add(base + 16, 1u, __ATOMIC_RELAXED, AGT);
        while (__hip_atomic_load(base + 16, __ATOMIC_RELAXED, AGT) < n)
            __builtin_amdgcn_s_sleep(2);
    }
    __syncthreads();
}

// Persistent kernel, 512 blocks x 512 threads, 2 blocks/CU = 16 waves/CU.
// Fused-role block: waves 0-3 = R12 A-path (conv1+LIF1+WTA strip) + L3;
// waves 4-7 = R12 B-path (pool1+conv2+LIF2+WTA+pool2 tile). Roles share
// stage syncs so A compute overlaps B's sc1/LDS stalls on the same CU.
// __launch_bounds__(512,2): empirical VGPR cap 256/w -> 128 (no spills;
// R15's (512,4) clamped to 64 VGPR -> 394 MB spill traffic). w3 weights
// moved to LDS to keep A-path natural demand < 128.
// Superstep k (k=0..6): A(4k..4k+3) ; L3(4k-8..4k-5) ; B(4k-4..4k-1).
__global__ __launch_bounds__(512, 2) void spike_persist(
    const float* __restrict__ x,    // (20,8,1,256,256)
    const float* __restrict__ w1,   // (4,1,5,5)
    const float* __restrict__ w2,   // (36,4,5,5)
    const float* __restrict__ w3,   // (1,36,7,7)
    float* __restrict__ out,        // (20,8,1,21,21)
    uint8_t* __restrict__ s1b,      // 8 buffers of u16[8][128][128]
    uint8_t* __restrict__ p2b,      // 8 buffers of u64[8][441]
    uint32_t* __restrict__ bar)
{
    __shared__ float    xs[2112];    // A: 8 x 264 input rows (halo 2)
    __shared__ uint64_t st64[279];   // B: staged s1m 31 rows x 9 u64
    __shared__ float    ps[400];     // B: 4 ch x 10 x 10 pooled tile (halo 2)
    __shared__ float    mem_s[1296]; // B: 36 ch x 36 planes (pitch 6)
    __shared__ float    bm_s[324];   // B: 36 ch x 9 blocks (pitch 3)
    __shared__ int      wc_s[36];
    __shared__ uint32_t p2a[18];     // B: 9 cells x 2 words of channel bits
    __shared__ float    w3s[1764];   // conv3 weights (shared by A waves)

    const int tid = threadIdx.x;
    const int bid = blockIdx.x;
    const int bt = bid >> 6;         // batch (both roles)
    const bool isA = tid < 256;
    const int btid = tid & 255;      // role-local tid
    const int wv = (tid >> 6) & 3;   // role-local wave 0..3
    const int lane = tid & 63;
    uint32_t nbar = 0;

    // stage w3 into LDS (t-invariant; first read is many syncs later)
    for (int idx = tid; idx < 1764; idx += 512) w3s[idx] = w3[idx];

    // ================= role-local state =================
    float m1r[4][2][2];
    int aoff[9]; uint32_t avalm = 0; int s1soff64 = 0;
    float m3r[2] = {0.f, 0.f};
    bool l3in[2], l3v[2]; int l3o[2]; int lid3 = 0;
    float m2r[9];
    int boff[2]; uint32_t bvalm = 0; int d16 = 0;
    int oy2 = 0, ox2 = 0, th2 = 0, tw2 = 0;
    bool act = false; int prA = 0, pcA = 0;
    uint64_t pf0 = 0, pf1 = 0;

    if (isA) {
        const int r0 = (bid & 63) * 4;
        const int tr = tid >> 7, tc = tid & 127;
#pragma unroll
        for (int c = 0; c < 4; c++)
#pragma unroll
            for (int dy = 0; dy < 2; dy++)
#pragma unroll
                for (int dx = 0; dx < 2; dx++) m1r[c][dy][dx] = 0.f;
#pragma unroll
        for (int i = 0; i < 9; i++) {
            int idx = tid + i * 256;
            int row = idx / 264, col = idx - row * 264;
            int gy = r0 + row - 2, gx = col - 2;
            if ((idx < 2112) && gy >= 0 && gy < 256 && gx >= 0 && gx < 256)
                avalm |= 1u << i;
            aoff[i] = gy * 256 + gx;
        }
        s1soff64 = (bt * 128 + (r0 >> 1) + tr) * 32 + (tc >> 2);
        lid3 = (bid & 63) * 4 + wv;
        const int kyl = lane / 7, kxl = lane % 7;
#pragma unroll
        for (int rep = 0; rep < 2; rep++) {
            int o = lid3 + rep * 256;
            int rr = o / 21, cl = o - rr * 21;
            int yy = rr + kyl - 3, xx = cl + kxl - 3;
            l3in[rep] = o < 441;
            l3v[rep] = (o < 441) && (lane < 49) && yy >= 0 && yy < 21 && xx >= 0 && xx < 21;
            l3o[rep] = bt * 441 + yy * 21 + xx;      // u64 units
        }
    } else {
        const int tIdx = bid & 63;
        const int tyi = tIdx >> 3, txi = tIdx & 7;
        oy2 = tyi < 5 ? 6 * tyi : 30 + 4 * (tyi - 5);
        ox2 = txi < 5 ? 6 * txi : 30 + 4 * (txi - 5);
        th2 = tyi < 5 ? 6 : 4;
        tw2 = txi < 5 ? 6 : 4;
        const int pr = lane / 6, pc = lane - 6 * pr;
        act = (pr < th2) && (pc < tw2);
        prA = pr > 5 ? 0 : pr; pcA = pc;
#pragma unroll
        for (int i = 0; i < 9; i++) m2r[i] = 0.f;
        const int rb0 = 3 * oy2 - 6;
        const int cb0 = (3 * ox2 - 6) >> 1;
        const int cq0 = cb0 >> 1;
        d16 = 2 * (cb0 & 1);
#pragma unroll
        for (int i = 0; i < 2; i++) {
            int idx = btid + i * 256;
            int row = idx / 9, q = idx - 9 * row;
            int grow = rb0 + row;
            int ucol = 2 * (cq0 + q);
            if ((idx < 279) && grow >= 0 && grow < 128 && ucol >= 0 && ucol < 64)
                bvalm |= 1u << i;
            boff[i] = (bt * 128 + grow) * 32 + cq0 + q;
        }
    }

    for (int k = 0; k < 7; k++) {
        // post-barrier prefetch of tt=0's B staging
        if (!isA) {
            int tb0 = 4 * k - 4;
            if (tb0 >= 0 && tb0 < 20) {
                const uint64_t* s1r64 = reinterpret_cast<const uint64_t*>(
                    s1b + (size_t)(tb0 & 7) * 262144);
                pf0 = (bvalm & 1u) ? ldu64(s1r64 + boff[0]) : 0ull;
                pf1 = (bvalm & 2u) ? ldu64(s1r64 + boff[1]) : 0ull;
            }
        }

        for (int tt = 0; tt < 4; tt++) {
            const int t = 4 * k + tt;
            const int tb = 4 * k - 4 + tt;
            const int tl = 4 * k - 8 + tt;
            const bool tok = t < 20;
            const bool tbok = (tb >= 0) && (tb < 20);
            const bool tlok = (tl >= 0) && (tl < 20);

            // ---------- S1: A stage xs ; B write staged s1 to LDS ----------
            if (isA && tok) {
                const float* xb = x + ((size_t)t * 8 + bt) * 65536;
#pragma unroll
                for (int i = 0; i < 9; i++) {
                    int idx = tid + i * 256;
                    if (idx < 2112) xs[idx] = ((avalm >> i) & 1u) ? xb[aoff[i]] : 0.f;
                }
            } else if (!isA && tbok) {
                st64[btid] = pf0;
                if (btid + 256 < 279) st64[btid + 256] = pf1;
            }
            __syncthreads();

            // ---------- S2: A conv1+LIF1+WTA+store ; B pool ----------
            if (isA && tok) {
                uint64_t* s1w = reinterpret_cast<uint64_t*>(s1b + (size_t)(t & 7) * 262144);
                const int tr = tid >> 7, tc = tid & 127;
                const float2* xs2 = reinterpret_cast<const float2*>(xs);
                float p[6][6];
#pragma unroll
                for (int i = 0; i < 6; i++)
#pragma unroll
                    for (int j = 0; j < 3; j++) {
                        float2 v = xs2[(2 * tr + i) * 132 + tc + j];
                        p[i][2 * j] = v.x; p[i][2 * j + 1] = v.y;
                    }

                float acc[4][2][2];
#pragma unroll
                for (int c = 0; c < 4; c++)
#pragma unroll
                    for (int dy = 0; dy < 2; dy++)
#pragma unroll
                        for (int dx = 0; dx < 2; dx++) acc[c][dy][dx] = 0.f;
#pragma unroll
                for (int c = 0; c < 4; c++)
#pragma unroll
                    for (int ky = 0; ky < 5; ky++)
#pragma unroll
                        for (int kx = 0; kx < 5; kx++) {
                            float w = w1[c * 25 + ky * 5 + kx];
#pragma unroll
                            for (int dy = 0; dy < 2; dy++)
#pragma unroll
                                for (int dx = 0; dx < 2; dx++)
                                    acc[c][dy][dx] = fmaf(p[dy + ky][dx + kx], w, acc[c][dy][dx]);
                        }

                float mem[4][2][2];
#pragma unroll
                for (int c = 0; c < 4; c++)
#pragma unroll
                    for (int dy = 0; dy < 2; dy++)
#pragma unroll
                        for (int dx = 0; dx < 2; dx++)
                            mem[c][dy][dx] = m1r[c][dy][dx] + acc[c][dy][dx];

                int wc[2][2];
#pragma unroll
                for (int dy = 0; dy < 2; dy++)
#pragma unroll
                    for (int dx = 0; dx < 2; dx++) {
                        int w = 0; float mx = mem[0][dy][dx];
#pragma unroll
                        for (int c = 1; c < 4; c++) {
                            float v = mem[c][dy][dx];
                            if (v > mx) { mx = v; w = c; }
                        }
                        wc[dy][dx] = w;
                    }

                float bm[4];
#pragma unroll
                for (int c = 0; c < 4; c++)
                    bm[c] = fmaxf(fmaxf(mem[c][0][0], mem[c][0][1]),
                                  fmaxf(mem[c][1][0], mem[c][1][1]));

                uint32_t bits = 0;
#pragma unroll
                for (int c = 0; c < 4; c++)
#pragma unroll
                    for (int dy = 0; dy < 2; dy++)
#pragma unroll
                        for (int dx = 0; dx < 2; dx++) {
                            float m = mem[c][dy][dx];
                            bool s = (m >= THR) && (wc[dy][dx] == c) && (m >= bm[c]);
                            m1r[c][dy][dx] = fmaxf((s ? 0.f : m) - 9.0f, 0.f);
                            bits |= (s ? 1u : 0u) << (c * 4 + dy * 2 + dx);
                        }
                uint32_t b32 = bits | ((uint32_t)__shfl_xor((int)bits, 1, 64) << 16);
                uint64_t b64 = (uint64_t)b32 |
                               ((uint64_t)(uint32_t)__shfl_xor((int)b32, 2, 64) << 32);
                if (!(tid & 3)) stu64(s1w + s1soff64, b64);
            } else if (!isA && tbok) {
                if (btid < 100) {
                    int r = btid / 10, cc2 = btid - 10 * (btid / 10);
                    int gy = oy2 - 2 + r, gx = ox2 - 2 + cc2;
                    uint32_t accb = 0;
                    if (r < th2 + 4 && cc2 < tw2 + 4 && gy >= 0 && gy < 42 && gx >= 0 && gx < 42) {
                        const uint16_t* st16 = reinterpret_cast<const uint16_t*>(st64);
#pragma unroll
                        for (int kr = 0; kr < 4; kr++)
#pragma unroll
                            for (int kc = 0; kc < 4; kc++) {
                                uint32_t m = (kr < 3) ? (kc < 3 ? 0xFu : 0x5u)
                                                      : (kc < 3 ? 0x3u : 0x1u);
                                uint32_t v = st16[(3 * r + kr) * 36 + 3 * cc2 + kc + d16];
                                accb |= v & (m * 0x1111u);
                            }
                    }
#pragma unroll
                    for (int ic = 0; ic < 4; ic++)
                        ps[ic * 100 + btid] = ((accb >> (4 * ic)) & 0xFu) ? 1.f : 0.f;
                }
            }
            __syncthreads();

            // ---------- S3: A does L3(tl) ; B conv2 + next prefetch ----------
            if (isA && tlok) {
                const uint64_t* pb64 = reinterpret_cast<const uint64_t*>(
                    p2b + (size_t)(tl & 7) * 32768);
#pragma unroll
                for (int rep = 0; rep < 2; rep++) {
                    if (l3in[rep]) {
                        int o = lid3 + rep * 256;
                        uint64_t v = l3v[rep] ? ldu64(pb64 + l3o[rep]) : 0ull;
                        uint32_t lo = (uint32_t)v, hi = (uint32_t)(v >> 32);
                        float accv = 0.f;
#pragma unroll
                        for (int c = 0; c < 32; c++)
                            accv += ((lo >> c) & 1u) ? w3s[c * 49 + lane] : 0.f;
#pragma unroll
                        for (int c = 0; c < 4; c++)
                            accv += ((hi >> c) & 1u) ? w3s[(32 + c) * 49 + lane] : 0.f;
#pragma unroll
                        for (int off = 32; off; off >>= 1) accv += __shfl_xor(accv, off, 64);
                        float memv3 = m3r[rep] + accv;
                        bool s = memv3 >= THR;
                        if (lane == 0) out[(size_t)tl * 3528 + bt * 441 + o] = s ? 1.f : 0.f;
                        m3r[rep] = fmaxf(s ? 0.f : memv3, 0.f);
                    }
                }
            } else if (!isA && tbok) {
                float pv[4][5][5];
#pragma unroll
                for (int ic = 0; ic < 4; ic++)
#pragma unroll
                    for (int i = 0; i < 5; i++)
#pragma unroll
                        for (int j = 0; j < 5; j++)
                            pv[ic][i][j] = ps[ic * 100 + (prA + i) * 10 + (pcA + j)];

                {
                    int tbn = tb + 1;
                    if (tt < 3 && tbn >= 0 && tbn < 20) {
                        const uint64_t* s1r64 = reinterpret_cast<const uint64_t*>(
                            s1b + (size_t)(tbn & 7) * 262144);
                        pf0 = (bvalm & 1u) ? ldu64(s1r64 + boff[0]) : 0ull;
                        pf1 = (bvalm & 2u) ? ldu64(s1r64 + boff[1]) : 0ull;
                    }
                }

                for (int cc = 0; cc < 9; cc++) {
                    int c = cc * 4 + wv;                         // wave-uniform
                    const float* wr = w2 + (size_t)__builtin_amdgcn_readfirstlane(c) * 100;
                    float accv = 0.f;
#pragma unroll
                    for (int ic = 0; ic < 4; ic++)
#pragma unroll
                        for (int i = 0; i < 5; i++)
#pragma unroll
                            for (int j = 0; j < 5; j++)
                                accv = fmaf(pv[ic][i][j], wr[ic * 25 + i * 5 + j], accv);
                    float m = act ? (m2r[cc] + accv) : -1e30f;
                    if (lane < 36) mem_s[c * 36 + lane] = m;     // plane == lane
                }
            }
            __syncthreads();

            // ---------- S4: B wc_s + bm_s + p2a zero ----------
            if (!isA && tbok) {
                if (btid < 36) {
                    float mx = mem_s[btid]; int w = 0;
#pragma unroll
                    for (int c = 1; c < 36; c++) {
                        float v = mem_s[c * 36 + btid];
                        if (v > mx) { mx = v; w = c; }
                    }
                    wc_s[btid] = w;
                }
#pragma unroll
                for (int i = 0; i < 2; i++) {
                    int idx = btid + i * 256;
                    if (idx < 324) {
                        int c = idx / 9, blk = idx - 9 * c;
                        int br = blk / 3, bc2 = blk - 3 * br;
                        int l0 = 12 * br + 2 * bc2;
                        float a = mem_s[c * 36 + l0],     bb2 = mem_s[c * 36 + l0 + 1];
                        float d = mem_s[c * 36 + l0 + 6], e   = mem_s[c * 36 + l0 + 7];
                        bm_s[idx] = fmaxf(fmaxf(a, bb2), fmaxf(d, e));
                    }
                }
                if (btid < 18) p2a[btid] = 0;
            }
            __syncthreads();

            // ---------- S5: B m2r update + any/atomicOr ----------
            if (!isA && tbok) {
                const int pr = lane / 6, pc = lane - 6 * pr;
                const int blkl = (pr >> 1) * 3 + (pc >> 1);
                for (int cc = 0; cc < 9; cc++) {
                    int c = cc * 4 + wv;
                    if (act) {
                        float m = mem_s[c * 36 + lane];
                        bool s = (m >= THR) && (wc_s[lane] == c) && (m >= bm_s[c * 9 + blkl]);
                        m2r[cc] = fmaxf((s ? 0.f : m) - 1.0f, 0.f);
                    }
                }
#pragma unroll
                for (int i = 0; i < 2; i++) {
                    int idx = btid + i * 256;
                    if (idx < 324) {
                        int c = idx / 9, blk = idx - 9 * c;
                        int br = blk / 3, bc2 = blk - 3 * br;
                        if (2 * br < th2 && 2 * bc2 < tw2) {
                            int l0 = 12 * br + 2 * bc2;
                            float bmv = bm_s[idx];
                            bool any = false;
#pragma unroll
                            for (int kk = 0; kk < 4; kk++) {
                                int l = l0 + (kk >> 1) * 6 + (kk & 1);
                                float m = mem_s[c * 36 + l];
                                any |= (m >= THR) && (wc_s[l] == c) && (m >= bmv);
                            }
                            if (any)
                                atomicOr(&p2a[(blk << 1) + (c >> 5)], 1u << (c & 31));
                        }
                    }
                }
            }
            __syncthreads();

            // ---------- S6: B p2 store ----------
            if (!isA && tbok) {
                if (btid < 9) {
                    int br = btid / 3, bc2 = btid - 3 * br;
                    if (2 * br < th2 && 2 * bc2 < tw2) {
                        uint64_t* p2w64 = reinterpret_cast<uint64_t*>(
                            p2b + (size_t)(tb & 7) * 32768);
                        int cell = bt * 441 + ((oy2 >> 1) + br) * 21 + (ox2 >> 1) + bc2;
                        uint64_t v = (uint64_t)p2a[btid * 2] |
                                     ((uint64_t)p2a[btid * 2 + 1] << 32);
                        stu64(p2w64 + cell, v);
                    }
                }
            }
            // no sync here: next S1 touches xs/st64 only, protected by S1's sync
        }

        if (k < 6) gbar(bar, bid, ++nbar);
    }
}

extern "C" void kernel_launch(void* const* d_in, const int* in_sizes, int n_in,
                              void* d_out, int out_size, void* d_ws, size_t ws_size,
                              hipStream_t stream) {
    const float* x  = (const float*)d_in[0];
    const float* w1 = (const float*)d_in[1];
    const float* w2 = (const float*)d_in[2];
    const float* w3 = (const float*)d_in[3];
    float* out = (float*)d_out;
    uint8_t* s1 = (uint8_t*)d_ws;
    uint8_t* p2 = (uint8_t*)d_ws + OFF_P2;
    uint32_t* bar = (uint32_t*)((char*)d_ws + OFF_BAR);

    zero_bar<<<1, 256, 0, stream>>>(bar);

    void* args[] = {(void*)&x, (void*)&w1, (void*)&w2, (void*)&w3,
                    (void*)&out, (void*)&s1, (void*)&p2, (void*)&bar};
    hipLaunchCooperativeKernel((void*)spike_persist, dim3(512), dim3(512),
                               args, 0, stream);
}

// Round 17
// 397.151 us; speedup vs baseline: 2.1394x; 1.3967x over previous
//
#include <hip/hip_runtime.h>
#include <stdint.h>

#define THR 10.0f
#define AGT __HIP_MEMORY_SCOPE_AGENT

// ---- workspace layout (bytes) ----
// s1m x8 (u16 per 2x2 block): 8 * 262,144 = 2,097,152 at 0            (t & 7)
// p2m x8 (u64 per cell):      8 *  32,768 =   262,144 at 2,097,152    (t & 7)
// barrier: u32[256] at 2,359,296
static constexpr size_t OFF_P2  = 2097152;
static constexpr size_t OFF_BAR = 2359296;

static __device__ __forceinline__ uint64_t ldu64(const uint64_t* p) {
    return __hip_atomic_load(p, __ATOMIC_RELAXED, AGT);
}
static __device__ __forceinline__ void stu64(uint64_t* p, uint64_t v) {
    __hip_atomic_store(p, v, __ATOMIC_RELAXED, AGT);
}

__global__ __launch_bounds__(256) void zero_bar(uint32_t* __restrict__ bar) {
    if (threadIdx.x < 256) bar[threadIdx.x] = 0u;
}

// Group-local barrier (64 blocks of one batch group); all dataflow is
// intra-group. bar[g*32]: arrival counter (RMW); bar[g*32+16]: go epoch
// (polled with relaxed agent LOAD).
__device__ __forceinline__ void gbar(uint32_t* bar, int bid, uint32_t n) {
    __syncthreads();                       // drains vmcnt: sc1 stores done
    if (threadIdx.x == 0) {
        uint32_t* base = bar + (bid >> 6) * 32;
        uint32_t a = __hip_atomic_fetch_add(base, 1u, __ATOMIC_RELAXED, AGT);
        if (a == 64u * n - 1u)
            __hip_atomic_fetch_add(base + 16, 1u, __ATOMIC_RELAXED, AGT);
        while (__hip_atomic_load(base + 16, __ATOMIC_RELAXED, AGT) < n)
            __builtin_amdgcn_s_sleep(2);
    }
    __syncthreads();
}

// Persistent kernel, 512 blocks x 256 threads (R12 structure — the verified
// optimum of this design space; every structural variant measured worse).
// Two independent blocks per CU slip freely against each other, which beats
// all explicit role-overlap schemes tried (R13/R15/R16).
// Superstep k (k=0..6): A(4k..4k+3) ; L3(4k-8..4k-5) ; B(4k-4..4k-1).
// All cross-block traffic uses 64-bit agent-scope transactions:
// A merges 4 threads' u16 spike masks into one u64 store; B stages 279 u64
// per tile; L3 reads/writes p2 cells as single u64.
__global__ __launch_bounds__(256, 2) void spike_persist(
    const float* __restrict__ x,    // (20,8,1,256,256)
    const float* __restrict__ w1,   // (4,1,5,5)
    const float* __restrict__ w2,   // (36,4,5,5)
    const float* __restrict__ w3,   // (1,36,7,7)
    float* __restrict__ out,        // (20,8,1,21,21)
    uint8_t* __restrict__ s1b,      // 8 buffers of u16[8][128][128]
    uint8_t* __restrict__ p2b,      // 8 buffers of u64[8][441]
    uint32_t* __restrict__ bar)
{
    __shared__ union {
        float    xs[2112];           // phase A: 8 x 264 input rows (halo 2)
        uint64_t st64[279];          // phase B: staged s1m 31 rows x 9 u64
    } u;
    __shared__ float    ps[400];     // 4 ch x 10 x 10 pooled tile (halo 2)
    __shared__ float    mem_s[1296]; // 36 ch x 36 planes (pitch 6)
    __shared__ float    bm_s[324];   // 36 ch x 9 blocks (pitch 3)
    __shared__ int      wc_s[36];
    __shared__ uint32_t p2a[18];     // 9 cells x 2 words of channel bits

    const int tid = threadIdx.x;
    const int bid = blockIdx.x;
    uint32_t nbar = 0;

    // ---- L1 ownership: 512 blocks = 8 b x 64 row-strips (4 rows each)
    const int b1 = bid >> 6;
    const int r0 = (bid & 63) * 4;
    const int tr = tid >> 7, tc = tid & 127;

    // ---- L2 ownership: 512 blocks = 8 b x 64 tiles (8x8, uneven splits)
    const int tIdx = bid & 63;
    const int b2 = bid >> 6;
    const int tyi = tIdx >> 3, txi = tIdx & 7;
    const int oy2 = tyi < 5 ? 6 * tyi : 30 + 4 * (tyi - 5);
    const int ox2 = txi < 5 ? 6 * txi : 30 + 4 * (txi - 5);
    const int th2 = tyi < 5 ? 6 : 4;
    const int tw2 = txi < 5 ? 6 : 4;
    const int wave = tid >> 6, lane = tid & 63;
    const int pr = lane / 6, pc = lane - 6 * pr;     // plane == lane for lane<36
    const bool act = (pr < th2) && (pc < tw2);
    const int prA = pr > 5 ? 0 : pr, pcA = pc;

    // ---- L3 ownership: group-local. lid3 in [0,256); outputs lid3, lid3+256
    const int lid3 = (bid & 63) * 4 + wave;
    const int kyl = lane / 7, kxl = lane % 7;

    // hoist w3 into registers (t-invariant)
    float w3v[36];
#pragma unroll
    for (int c = 0; c < 36; c++) w3v[c] = (lane < 49) ? w3[c * 49 + lane] : 0.f;

    // ---- t-invariant address precompute ----
    int aoff[9]; uint32_t avalm = 0;
#pragma unroll
    for (int i = 0; i < 9; i++) {
        int idx = tid + i * 256;
        int row = idx / 264, col = idx - row * 264;
        int gy = r0 + row - 2, gx = col - 2;
        if ((idx < 2112) && gy >= 0 && gy < 256 && gx >= 0 && gx < 256)
            avalm |= 1u << i;
        aoff[i] = gy * 256 + gx;
    }
    const int s1soff64 = (b1 * 128 + (r0 >> 1) + tr) * 32 + (tc >> 2);

    const int rb0 = 3 * oy2 - 6;
    const int cb0 = (3 * ox2 - 6) >> 1;          // u32 col (can be odd/neg)
    const int cq0 = cb0 >> 1;                    // u64 col (floor)
    const int d16 = 2 * (cb0 & 1);               // u16 offset inside window
    int boff[2]; uint32_t bvalm = 0;
#pragma unroll
    for (int i = 0; i < 2; i++) {
        int idx = tid + i * 256;
        int row = idx / 9, q = idx - 9 * row;
        int grow = rb0 + row;
        int ucol = 2 * (cq0 + q);
        if ((idx < 279) && grow >= 0 && grow < 128 && ucol >= 0 && ucol < 64)
            bvalm |= 1u << i;
        boff[i] = (b2 * 128 + grow) * 32 + cq0 + q;
    }

    bool l3in[2], l3v[2]; int l3o[2];
#pragma unroll
    for (int rep = 0; rep < 2; rep++) {
        int o = lid3 + rep * 256;
        int rr = o / 21, cl = o - rr * 21;
        int yy = rr + kyl - 3, xx = cl + kxl - 3;
        l3in[rep] = o < 441;
        l3v[rep] = (o < 441) && (lane < 49) && yy >= 0 && yy < 21 && xx >= 0 && xx < 21;
        l3o[rep] = b2 * 441 + yy * 21 + xx;      // u64 units
    }

    float m1r[4][2][2];
#pragma unroll
    for (int c = 0; c < 4; c++)
#pragma unroll
        for (int dy = 0; dy < 2; dy++)
#pragma unroll
            for (int dx = 0; dx < 2; dx++) m1r[c][dy][dx] = 0.f;
    float m2r[9];
#pragma unroll
    for (int i = 0; i < 9; i++) m2r[i] = 0.f;
    float m3r[2] = {0.f, 0.f};

    for (int k = 0; k < 7; k++) {
        // ================= A(t=4k .. 4k+3) =================
        for (int tt = 0; tt < 4; tt++) {
            const int t = 4 * k + tt;
            if (t < 20) {
                uint64_t* s1w = reinterpret_cast<uint64_t*>(s1b + (size_t)(t & 7) * 262144);
                const float* xb = x + ((size_t)t * 8 + b1) * 65536;
                __syncthreads();               // prior union readers done
#pragma unroll
                for (int i = 0; i < 9; i++) {
                    int idx = tid + i * 256;
                    if (idx < 2112) u.xs[idx] = ((avalm >> i) & 1u) ? xb[aoff[i]] : 0.f;
                }
                __syncthreads();

                const float2* xs2 = reinterpret_cast<const float2*>(u.xs);
                float p[6][6];
#pragma unroll
                for (int i = 0; i < 6; i++)
#pragma unroll
                    for (int j = 0; j < 3; j++) {
                        float2 v = xs2[(2 * tr + i) * 132 + tc + j];
                        p[i][2 * j] = v.x; p[i][2 * j + 1] = v.y;
                    }

                float acc[4][2][2];
#pragma unroll
                for (int c = 0; c < 4; c++)
#pragma unroll
                    for (int dy = 0; dy < 2; dy++)
#pragma unroll
                        for (int dx = 0; dx < 2; dx++) acc[c][dy][dx] = 0.f;
#pragma unroll
                for (int c = 0; c < 4; c++)
#pragma unroll
                    for (int ky = 0; ky < 5; ky++)
#pragma unroll
                        for (int kx = 0; kx < 5; kx++) {
                            float w = w1[c * 25 + ky * 5 + kx];
#pragma unroll
                            for (int dy = 0; dy < 2; dy++)
#pragma unroll
                                for (int dx = 0; dx < 2; dx++)
                                    acc[c][dy][dx] = fmaf(p[dy + ky][dx + kx], w, acc[c][dy][dx]);
                        }

                float mem[4][2][2];
#pragma unroll
                for (int c = 0; c < 4; c++)
#pragma unroll
                    for (int dy = 0; dy < 2; dy++)
#pragma unroll
                        for (int dx = 0; dx < 2; dx++)
                            mem[c][dy][dx] = m1r[c][dy][dx] + acc[c][dy][dx];

                int wc[2][2];
#pragma unroll
                for (int dy = 0; dy < 2; dy++)
#pragma unroll
                    for (int dx = 0; dx < 2; dx++) {
                        int w = 0; float mx = mem[0][dy][dx];
#pragma unroll
                        for (int c = 1; c < 4; c++) {
                            float v = mem[c][dy][dx];
                            if (v > mx) { mx = v; w = c; }
                        }
                        wc[dy][dx] = w;
                    }

                float bm[4];
#pragma unroll
                for (int c = 0; c < 4; c++)
                    bm[c] = fmaxf(fmaxf(mem[c][0][0], mem[c][0][1]),
                                  fmaxf(mem[c][1][0], mem[c][1][1]));

                uint32_t bits = 0;
#pragma unroll
                for (int c = 0; c < 4; c++)
#pragma unroll
                    for (int dy = 0; dy < 2; dy++)
#pragma unroll
                        for (int dx = 0; dx < 2; dx++) {
                            float m = mem[c][dy][dx];
                            bool s = (m >= THR) && (wc[dy][dx] == c) && (m >= bm[c]);
                            m1r[c][dy][dx] = fmaxf((s ? 0.f : m) - 9.0f, 0.f);
                            bits |= (s ? 1u : 0u) << (c * 4 + dy * 2 + dx);
                        }
                uint32_t b32 = bits | ((uint32_t)__shfl_xor((int)bits, 1, 64) << 16);
                uint64_t b64 = (uint64_t)b32 |
                               ((uint64_t)(uint32_t)__shfl_xor((int)b32, 2, 64) << 32);
                if (!(tid & 3)) stu64(s1w + s1soff64, b64);
            }
        }

        // ================= L3(t=4k-8 .. 4k-5) : own batch only ========
        for (int tt = 0; tt < 4; tt++) {
            const int tl = 4 * k - 8 + tt;
            if (tl >= 0 && tl < 20) {
                const uint64_t* pb64 = reinterpret_cast<const uint64_t*>(
                    p2b + (size_t)(tl & 7) * 32768);
#pragma unroll
                for (int rep = 0; rep < 2; rep++) {
                    if (l3in[rep]) {
                        int o = lid3 + rep * 256;
                        uint64_t v = l3v[rep] ? ldu64(pb64 + l3o[rep]) : 0ull;
                        uint32_t lo = (uint32_t)v, hi = (uint32_t)(v >> 32);
                        float accv = 0.f;
#pragma unroll
                        for (int c = 0; c < 32; c++) accv += ((lo >> c) & 1u) ? w3v[c] : 0.f;
#pragma unroll
                        for (int c = 0; c < 4; c++)  accv += ((hi >> c) & 1u) ? w3v[32 + c] : 0.f;
#pragma unroll
                        for (int off = 32; off; off >>= 1) accv += __shfl_xor(accv, off, 64);
                        float memv3 = m3r[rep] + accv;
                        bool s = memv3 >= THR;
                        if (lane == 0) out[(size_t)tl * 3528 + b2 * 441 + o] = s ? 1.f : 0.f;
                        m3r[rep] = fmaxf(s ? 0.f : memv3, 0.f);
                    }
                }
            }
        }

        // ================= B(t=4k-4 .. 4k-1) =================
        for (int tt = 0; tt < 4; tt++) {
            const int tb = 4 * k - 4 + tt;
            if (tb >= 0 && tb < 20) {
                const uint64_t* s1r64 = reinterpret_cast<const uint64_t*>(
                    s1b + (size_t)(tb & 7) * 262144);
                uint64_t* p2w64 = reinterpret_cast<uint64_t*>(p2b + (size_t)(tb & 7) * 32768);

                __syncthreads();   // prior union readers done
#pragma unroll
                for (int i = 0; i < 2; i++) {
                    int idx = tid + i * 256;
                    if (idx < 279)
                        u.st64[idx] = ((bvalm >> i) & 1u) ? ldu64(s1r64 + boff[i]) : 0ull;
                }
                if (tid < 18) p2a[tid] = 0;
                __syncthreads();

                // pool 7x7/6 as bitwise OR with edge nibble-masks -> ps
                if (tid < 100) {
                    int r = tid / 10, cc2 = tid - 10 * (tid / 10);
                    int gy = oy2 - 2 + r, gx = ox2 - 2 + cc2;
                    uint32_t accb = 0;
                    if (r < th2 + 4 && cc2 < tw2 + 4 && gy >= 0 && gy < 42 && gx >= 0 && gx < 42) {
                        const uint16_t* st16 = reinterpret_cast<const uint16_t*>(u.st64);
#pragma unroll
                        for (int kr = 0; kr < 4; kr++)
#pragma unroll
                            for (int kc = 0; kc < 4; kc++) {
                                uint32_t m = (kr < 3) ? (kc < 3 ? 0xFu : 0x5u)
                                                      : (kc < 3 ? 0x3u : 0x1u);
                                uint32_t v = st16[(3 * r + kr) * 36 + 3 * cc2 + kc + d16];
                                accb |= v & (m * 0x1111u);
                            }
                    }
#pragma unroll
                    for (int ic = 0; ic < 4; ic++)
                        ps[ic * 100 + tid] = ((accb >> (4 * ic)) & 0xFu) ? 1.f : 0.f;
                }
                __syncthreads();

                float pv[4][5][5];
#pragma unroll
                for (int ic = 0; ic < 4; ic++)
#pragma unroll
                    for (int i = 0; i < 5; i++)
#pragma unroll
                        for (int j = 0; j < 5; j++)
                            pv[ic][i][j] = ps[ic * 100 + (prA + i) * 10 + (pcA + j)];

                float memv[9];
                for (int cc = 0; cc < 9; cc++) {
                    int c = cc * 4 + wave;                       // wave-uniform
                    const float* wr = w2 + (size_t)__builtin_amdgcn_readfirstlane(c) * 100;
                    float accv = 0.f;
#pragma unroll
                    for (int ic = 0; ic < 4; ic++)
#pragma unroll
                        for (int i = 0; i < 5; i++)
#pragma unroll
                            for (int j = 0; j < 5; j++)
                                accv = fmaf(pv[ic][i][j], wr[ic * 25 + i * 5 + j], accv);
                    float m = act ? (m2r[cc] + accv) : -1e30f;
                    memv[cc] = m;
                    if (lane < 36) mem_s[c * 36 + lane] = m;     // plane == lane
                }
                __syncthreads();

                if (tid < 36) {
                    float mx = mem_s[tid]; int w = 0;
#pragma unroll
                    for (int c = 1; c < 36; c++) {
                        float v = mem_s[c * 36 + tid];
                        if (v > mx) { mx = v; w = c; }
                    }
                    wc_s[tid] = w;
                }
#pragma unroll
                for (int i = 0; i < 2; i++) {
                    int idx = tid + i * 256;
                    if (idx < 324) {
                        int c = idx / 9, blk = idx - 9 * c;
                        int br = blk / 3, bc2 = blk - 3 * br;
                        int l0 = 12 * br + 2 * bc2;
                        float a = mem_s[c * 36 + l0],     bb2 = mem_s[c * 36 + l0 + 1];
                        float d = mem_s[c * 36 + l0 + 6], e   = mem_s[c * 36 + l0 + 7];
                        bm_s[idx] = fmaxf(fmaxf(a, bb2), fmaxf(d, e));
                    }
                }
                __syncthreads();

                const int blkl = (pr >> 1) * 3 + (pc >> 1);
                for (int cc = 0; cc < 9; cc++) {
                    int c = cc * 4 + wave;
                    if (act) {
                        float m = memv[cc];
                        bool s = (m >= THR) && (wc_s[lane] == c) && (m >= bm_s[c * 9 + blkl]);
                        m2r[cc] = fmaxf((s ? 0.f : m) - 1.0f, 0.f);
                    }
                }

#pragma unroll
                for (int i = 0; i < 2; i++) {
                    int idx = tid + i * 256;
                    if (idx < 324) {
                        int c = idx / 9, blk = idx - 9 * c;
                        int br = blk / 3, bc2 = blk - 3 * br;
                        if (2 * br < th2 && 2 * bc2 < tw2) {
                            int l0 = 12 * br + 2 * bc2;
                            float bmv = bm_s[idx];
                            bool any = false;
#pragma unroll
                            for (int kk = 0; kk < 4; kk++) {
                                int l = l0 + (kk >> 1) * 6 + (kk & 1);
                                float m = mem_s[c * 36 + l];
                                any |= (m >= THR) && (wc_s[l] == c) && (m >= bmv);
                            }
                            if (any)
                                atomicOr(&p2a[(blk << 1) + (c >> 5)], 1u << (c & 31));
                        }
                    }
                }
                __syncthreads();

                if (tid < 9) {
                    int br = tid / 3, bc2 = tid - 3 * br;
                    if (2 * br < th2 && 2 * bc2 < tw2) {
                        int cell = b2 * 441 + ((oy2 >> 1) + br) * 21 + (ox2 >> 1) + bc2;
                        uint64_t v = (uint64_t)p2a[tid * 2] |
                                     ((uint64_t)p2a[tid * 2 + 1] << 32);
                        stu64(p2w64 + cell, v);
                    }
                }
            }
        }

        if (k < 6) gbar(bar, bid, ++nbar);
    }
}

extern "C" void kernel_launch(void* const* d_in, const int* in_sizes, int n_in,
                              void* d_out, int out_size, void* d_ws, size_t ws_size,
                              hipStream_t stream) {
    const float* x  = (const float*)d_in[0];
    const float* w1 = (const float*)d_in[1];
    const float* w2 = (const float*)d_in[2];
    const float* w3 = (const float*)d_in[3];
    float* out = (float*)d_out;
    uint8_t* s1 = (uint8_t*)d_ws;
    uint8_t* p2 = (uint8_t*)d_ws + OFF_P2;
    uint32_t* bar = (uint32_t*)((char*)d_ws + OFF_BAR);

    zero_bar<<<1, 256, 0, stream>>>(bar);

    void* args[] = {(void*)&x, (void*)&w1, (void*)&w2, (void*)&w3,
                    (void*)&out, (void*)&s1, (void*)&p2, (void*)&bar};
    hipLaunchCooperativeKernel((void*)spike_persist, dim3(512), dim3(256),
                               args, 0, stream);
}